// Round 3
// baseline (1954.691 us; speedup 1.0000x reference)
//
#include <hip/hip_runtime.h>

// Problem constants (fixed by reference)
#define DIM 2048
#define NH 16
#define HD 128
#define NB 2
#define SEQ 4096
#define QKVC (3*DIM)            // 6144
#define EPS 1e-6f
#define LOG2E 1.4426950408889634f
#define SM_SCALE 0.08838834764831845f  // 1/sqrt(128)

typedef unsigned short u16;
typedef unsigned int u32;
typedef __attribute__((ext_vector_type(8))) short bf16x8;   // 8 bf16 = 4 VGPR (guide §3)
typedef __attribute__((ext_vector_type(4))) float f32x4;

#define GAS __attribute__((address_space(1)))
#define LAS __attribute__((address_space(3)))

// async global->LDS, 16B per lane, LDS dest = wave-uniform base + lane*16
__device__ __forceinline__ void gl_lds16(const void* g, void* l) {
  __builtin_amdgcn_global_load_lds((const GAS void*)g, (LAS void*)l, 16, 0, 0);
}

__device__ __forceinline__ u16 f2bf(float f) {   // RNE f32 -> bf16
  u32 u = __float_as_uint(f);
  u += 0x7fffu + ((u >> 16) & 1u);
  return (u16)(u >> 16);
}
__device__ __forceinline__ float bf2f(u32 h) { return __uint_as_float(h << 16); }

// pack two f32 -> two bf16 (round-half-up) in one u32: [hi16(e1) | hi16(e0)]
__device__ __forceinline__ u32 pack_bf2(float e0, float e1) {
  u32 a = __float_as_uint(e1) + 0x8000u;
  u32 b = __float_as_uint(e0) + 0x8000u;
  return __builtin_amdgcn_perm(a, b, 0x07060302u);
}

// ---------------- kernel 1: x fp32 -> bf16 ----------------
__global__ __launch_bounds__(256) void cast_x(const float* __restrict__ x,
                                              u16* __restrict__ xb) {
  int i = (blockIdx.x * 256 + threadIdx.x) * 4;
  float4 v = *(const float4*)(x + i);
  u16 o0 = f2bf(v.x), o1 = f2bf(v.y), o2 = f2bf(v.z), o3 = f2bf(v.w);
  *(ushort4*)(xb + i) = make_ushort4(o0, o1, o2, o3);
}

// ---------------- kernel 2: W (2048x6144) fp32 -> Wt (6144x2048) bf16 ----------------
__global__ __launch_bounds__(256) void cast_tw(const float* __restrict__ W,
                                               u16* __restrict__ Wt) {
  __shared__ u16 t[32][33];
  int n0 = blockIdx.x * 32, k0 = blockIdx.y * 32;
  int x = threadIdx.x & 31, y = threadIdx.x >> 5;      // y in 0..7
#pragma unroll
  for (int i = 0; i < 4; i++) {
    int r = y + 8 * i;
    t[r][x] = f2bf(W[(size_t)(k0 + r) * QKVC + n0 + x]);
  }
  __syncthreads();
#pragma unroll
  for (int i = 0; i < 4; i++) {
    int r = y + 8 * i;
    Wt[(size_t)(n0 + r) * DIM + k0 + x] = t[x][r];
  }
}

// ---------------- kernel 3: qkv = xb @ Wt^T + bias (bf16 MFMA, m97 structure) ----------------
__global__ __launch_bounds__(256) void gemm_qkv(const u16* __restrict__ A,   // 8192x2048
                                                const u16* __restrict__ Bt,  // 6144x2048
                                                const float* __restrict__ bias,
                                                u16* __restrict__ C) {       // 8192x6144 bf16
  __shared__ __align__(16) u16 As[128 * 64];
  __shared__ __align__(16) u16 Bs[128 * 64];
  const int nt = blockIdx.x, mt = blockIdx.y;
  const int tid = threadIdx.x, w = tid >> 6, l = tid & 63;
  const int wm = (w & 1) * 64, wn = (w >> 1) * 64;
  const int lr = l & 15, quad = l >> 4;
  const int srow = l >> 3, scol = (l & 7) * 8;   // staging: 8 rows x 128B per 1KB issue
  f32x4 acc[4][4] = {};
  for (int k0 = 0; k0 < DIM; k0 += 64) {
#pragma unroll
    for (int i = 0; i < 4; i++) {
      int r = w * 32 + i * 8 + srow;
      gl_lds16(A + (size_t)(mt * 128 + r) * DIM + k0 + scol, As + (w * 32 + i * 8) * 64);
      gl_lds16(Bt + (size_t)(nt * 128 + r) * DIM + k0 + scol, Bs + (w * 32 + i * 8) * 64);
    }
    __syncthreads();
#pragma unroll
    for (int kk = 0; kk < 2; kk++) {
      bf16x8 a[4], b[4];
#pragma unroll
      for (int mi = 0; mi < 4; mi++)
        a[mi] = *(const bf16x8*)(As + (wm + mi * 16 + lr) * 64 + kk * 32 + quad * 8);
#pragma unroll
      for (int ni = 0; ni < 4; ni++)
        b[ni] = *(const bf16x8*)(Bs + (wn + ni * 16 + lr) * 64 + kk * 32 + quad * 8);
#pragma unroll
      for (int mi = 0; mi < 4; mi++)
#pragma unroll
        for (int ni = 0; ni < 4; ni++)
          acc[mi][ni] = __builtin_amdgcn_mfma_f32_16x16x32_bf16(a[mi], b[ni], acc[mi][ni], 0, 0, 0);
    }
    __syncthreads();
  }
  // epilogue: + bias, bf16 store. C/D layout: col=lane&15, row=quad*4+reg (m89/m91)
#pragma unroll
  for (int ni = 0; ni < 4; ni++) {
    int col = nt * 128 + wn + ni * 16 + lr;
    float bv = bias[col];
#pragma unroll
    for (int mi = 0; mi < 4; mi++) {
      int row = mt * 128 + wm + mi * 16 + quad * 4;
#pragma unroll
      for (int r = 0; r < 4; r++)
        C[(size_t)(row + r) * QKVC + col] = f2bf(acc[mi][ni][r] + bv);
    }
  }
}

// ---------------- kernel 4: RMSNorm + RoPE, split into Q,K,V (b,h,n,d) bf16 ----------------
// one wave per (token, head); lane l owns dims (2l, 2l+1) = one RoPE pair
// Q is pre-scaled by SM_SCALE*LOG2E so attn's exp2 needs no per-score multiply.
__global__ __launch_bounds__(256) void norm_rope(const u16* __restrict__ qkv,
                                                 const float* __restrict__ rot,
                                                 const float* __restrict__ qw,
                                                 const float* __restrict__ kw,
                                                 u16* __restrict__ Q, u16* __restrict__ K,
                                                 u16* __restrict__ V) {
  const int tok = blockIdx.x;                       // 0..8191  (b*4096+n)
  const int h = blockIdx.y * 4 + (threadIdx.x >> 6);
  const int l = threadIdx.x & 63;
  const int n = tok & (SEQ - 1);
  const size_t base = (size_t)tok * QKVC + h * 384 + 6 * l;  // elems; layout (d,j), j innermost
  const u32* p = (const u32*)(qkv + base);
  u32 u0 = p[0], u1 = p[1], u2 = p[2];
  float q0 = bf2f(u0 & 0xffff), k0 = bf2f(u0 >> 16);
  float v0 = bf2f(u1 & 0xffff), q1 = bf2f(u1 >> 16);
  float k1 = bf2f(u2 & 0xffff), v1 = bf2f(u2 >> 16);
  float sq = q0 * q0 + q1 * q1, sk = k0 * k0 + k1 * k1;
#pragma unroll
  for (int m = 1; m < 64; m <<= 1) {
    sq += __shfl_xor(sq, m, 64);
    sk += __shfl_xor(sk, m, 64);
  }
  float rq = rsqrtf(sq * (1.0f / HD) + EPS) * (SM_SCALE * LOG2E);  // scale folded into Q
  float rk = rsqrtf(sk * (1.0f / HD) + EPS);
  float2 wq = *(const float2*)(qw + 2 * l);
  float2 wk = *(const float2*)(kw + 2 * l);
  float4 rr = *(const float4*)(rot + (size_t)(n * 64 + l) * 4);  // [cos,-sin,sin,cos]
  float qh0 = q0 * rq * wq.x, qh1 = q1 * rq * wq.y;
  float kh0 = k0 * rk * wk.x, kh1 = k1 * rk * wk.y;
  float qo0 = rr.x * qh0 + rr.y * qh1, qo1 = rr.z * qh0 + rr.w * qh1;
  float ko0 = rr.x * kh0 + rr.y * kh1, ko1 = rr.z * kh0 + rr.w * kh1;
  const int bh = (tok >> 12) * NH + h;
  size_t o = ((size_t)bh * SEQ + n) * HD + 2 * l;
  *(u32*)(Q + o) = (u32)f2bf(qo0) | ((u32)f2bf(qo1) << 16);
  *(u32*)(K + o) = (u32)f2bf(ko0) | ((u32)f2bf(ko1) << 16);
  *(u32*)(V + o) = (u32)f2bf(v0) | ((u32)f2bf(v1) << 16);
}

// ---------------- kernel 5: V (bh,n,d) -> Vt (bh,d,n) ----------------
__global__ __launch_bounds__(256) void transpose_v(const u16* __restrict__ V,
                                                   u16* __restrict__ Vt) {
  __shared__ u16 t[64][65];
  const int nt = blockIdx.x, dt = blockIdx.y, bh = blockIdx.z;
  const int x = threadIdx.x & 63, y = threadIdx.x >> 6;   // y 0..3
  const size_t vb = (size_t)bh * SEQ * HD;
#pragma unroll
  for (int i = 0; i < 16; i++) {
    int r = y + 4 * i;
    t[r][x] = V[vb + (size_t)(nt * 64 + r) * HD + dt * 64 + x];
  }
  __syncthreads();
  const size_t ob = (size_t)bh * HD * SEQ;
#pragma unroll
  for (int i = 0; i < 16; i++) {
    int r = y + 4 * i;
    Vt[ob + (size_t)(dt * 64 + r) * SEQ + nt * 64 + x] = t[x][r];
  }
}

// ---------------- kernel 6: flash attention (S^T form, maxless softmax) ----------------
// block = (qt, bh): 128 Q rows; wave w owns Q rows w*32..w*32+31 (as MFMA *columns*).
// S^T = mfma(kf, qf): lanes = qrows, (quad,reg) = keys. Key permutation in Ks staging
// makes exp(S^T) pack in-register into a K=32 B-operand for O^T = mfma(vf, pf).
// Maxless softmax: |score| <= sqrt(128)*LOG2E ~ 16.3 in exp2 domain -> fp32 safe.
// Q arrives pre-scaled by SM_SCALE*LOG2E (folded in norm_rope).
// XOR chunk swizzle (chunk ^= row&7) on Ks/Vs kills the 16-way bank conflicts.
__global__ __launch_bounds__(256, 4) void attn(const u16* __restrict__ Q,
                                               const u16* __restrict__ K,
                                               const u16* __restrict__ Vt,
                                               float* __restrict__ out) {
  __shared__ __align__(16) u16 smem[8192 + 8192];  // Ks 64x128 + Vs 128x64 = 32 KB
  u16* Ks = smem;
  u16* Vs = smem + 8192;
  const int qt = blockIdx.x, bh = blockIdx.y;
  const int tid = threadIdx.x, w = tid >> 6, l = tid & 63;
  const int lr = l & 15, quad = l >> 4;
  const size_t qb = (size_t)bh * SEQ * HD;
  const size_t vb = (size_t)bh * HD * SEQ;

  // Q fragments direct from global (B-operand: n=qrow on lanes, k=quad*8+j)
  bf16x8 qf[2][4];
#pragma unroll
  for (int mi = 0; mi < 2; mi++)
#pragma unroll
    for (int ks = 0; ks < 4; ks++)
      qf[mi][ks] = *(const bf16x8*)(Q + qb + (size_t)(qt * 128 + w * 32 + mi * 16 + lr) * HD +
                                    ks * 32 + quad * 8);

  f32x4 oacc[2][8] = {};
  float lacc[2] = {0.f, 0.f};

  for (int kt = 0; kt < SEQ / 64; kt++) {
    // ---- stage K tile: 64 rows x 128 u16. LDS row rl holds PERMUTED key:
    //   rem=rl&31: key = (rl&32) + ((rem>>2)&3)*8 + (rem>>4)*4 + (rem&3)
    // column chunks xor-swizzled by (rl&7).
#pragma unroll
    for (int i = 0; i < 4; i++) {
      int rl = w * 16 + i * 4 + (l >> 4);
      int rem = rl & 31;
      int key = (rl & 32) + ((rem >> 2) & 3) * 8 + ((rem >> 4) << 2) + (rem & 3);
      int lc = (l & 15) ^ (rl & 7);
      gl_lds16(K + qb + (size_t)(kt * 64 + key) * HD + lc * 8, Ks + (w * 16 + i * 4) * 128);
    }
    // ---- stage V tile: 128 d-rows x 64 keys (natural key order), chunk-swizzled
#pragma unroll
    for (int i = 0; i < 4; i++) {
      int row = w * 32 + i * 8 + (l >> 3);
      int lc = (l & 7) ^ (row & 7);
      gl_lds16(Vt + vb + (size_t)row * SEQ + kt * 64 + lc * 8, Vs + (w * 32 + i * 8) * 64);
    }
    __syncthreads();

#pragma unroll
    for (int g = 0; g < 2; g++) {          // two 32-key groups per tile
      // K fragments (A-operand: m=key-slot on lanes, k=d)
      bf16x8 kf[2][4];
#pragma unroll
      for (int u = 0; u < 2; u++)
#pragma unroll
        for (int ks = 0; ks < 4; ks++) {
          int row = g * 32 + u * 16 + lr;
          int ch = (ks * 4 + quad) ^ (row & 7);
          kf[u][ks] = *(const bf16x8*)(Ks + row * 128 + ch * 8);
        }
      // S^T tiles: s[mi][u], lane holds (key = 32g+8*quad+4u+r, qrow = mi-tile + lr)
      f32x4 s[2][2] = {};
#pragma unroll
      for (int mi = 0; mi < 2; mi++)
#pragma unroll
        for (int u = 0; u < 2; u++)
#pragma unroll
          for (int ks = 0; ks < 4; ks++)
            s[mi][u] = __builtin_amdgcn_mfma_f32_16x16x32_bf16(kf[u][ks], qf[mi][ks], s[mi][u], 0, 0, 0);
      // exp (scale pre-folded into Q), accumulate l (fp32), pack P (round-half-up,
      // one v_perm per pair) as K=32 B-operand: j=4u+r -> key = 32g+8*quad+j
      bf16x8 pf[2];
#pragma unroll
      for (int mi = 0; mi < 2; mi++) {
#pragma unroll
        for (int u = 0; u < 2; u++)
#pragma unroll
          for (int r = 0; r < 4; r++) {
            float p = exp2f(s[mi][u][r]);
            s[mi][u][r] = p;
            lacc[mi] += p;
          }
        union { u32 w4[4]; bf16x8 v; } pk;
#pragma unroll
        for (int u = 0; u < 2; u++) {
          pk.w4[u * 2 + 0] = pack_bf2(s[mi][u][0], s[mi][u][1]);
          pk.w4[u * 2 + 1] = pack_bf2(s[mi][u][2], s[mi][u][3]);
        }
        pf[mi] = pk.v;
      }
      // O^T += V^T P^T : A = Vs[d][key] frag, B = pf. Result: m=d, lanes=qrow.
#pragma unroll
      for (int di = 0; di < 8; di++) {
        int row = di * 16 + lr;
        int ch = (4 * g + quad) ^ (row & 7);
        bf16x8 vf = *(const bf16x8*)(Vs + row * 64 + ch * 8);
        oacc[0][di] = __builtin_amdgcn_mfma_f32_16x16x32_bf16(vf, pf[0], oacc[0][di], 0, 0, 0);
        oacc[1][di] = __builtin_amdgcn_mfma_f32_16x16x32_bf16(vf, pf[1], oacc[1][di], 0, 0, 0);
      }
    }
    __syncthreads();   // Ks/Vs safe to overwrite next iter
  }

  // epilogue: reduce l across quads (2 shuffles, once), divide, coalesced float4 stores
  const int b = bh >> 4, h = bh & 15;
#pragma unroll
  for (int mi = 0; mi < 2; mi++) {
    float lsum = lacc[mi];
    lsum += __shfl_xor(lsum, 16, 64);
    lsum += __shfl_xor(lsum, 32, 64);
    float inv = 1.0f / lsum;
    int row = qt * 128 + w * 32 + mi * 16 + lr;
#pragma unroll
    for (int di = 0; di < 8; di++) {
      f32x4 o = oacc[mi][di];
      float4 v4 = make_float4(o[0] * inv, o[1] * inv, o[2] * inv, o[3] * inv);
      *(float4*)(out + ((size_t)(b * SEQ + row)) * DIM + h * HD + di * 16 + quad * 4) = v4;
    }
  }
}

// ---------------- launch ----------------
// ws layout (u16 elems; aliases are ordered by stream serialization):
//  [0        , 16777216)  xb   (later reused as Qb)
//  [16777216 , 29360128)  Wt
//  [29360128 , 79691776)  qkv  (first 16.8M elems later reused as Vt)
//  [79691776 , 96468992)  Kb
//  [96468992 ,113246208)  Vb
// total 226,492,416 bytes required of ws_size.
extern "C" void kernel_launch(void* const* d_in, const int* in_sizes, int n_in,
                              void* d_out, int out_size, void* d_ws, size_t ws_size,
                              hipStream_t stream) {
  (void)in_sizes; (void)n_in; (void)out_size; (void)ws_size;
  const float* x    = (const float*)d_in[0];
  const float* rot  = (const float*)d_in[1];
  const float* W    = (const float*)d_in[2];
  const float* bias = (const float*)d_in[3];
  const float* qw   = (const float*)d_in[4];
  const float* kw   = (const float*)d_in[5];
  float* out = (float*)d_out;
  u16* ws  = (u16*)d_ws;
  u16* xb  = ws;
  u16* Wt  = ws + 16777216;
  u16* qkv = ws + 29360128;
  u16* Qb  = ws;               // alias xb (dead after gemm)
  u16* Vt  = ws + 29360128;    // alias qkv (dead after norm_rope)
  u16* Kb  = ws + 79691776;
  u16* Vb  = ws + 96468992;

  hipLaunchKernelGGL(cast_x, dim3(16384), dim3(256), 0, stream, x, xb);
  hipLaunchKernelGGL(cast_tw, dim3(192, 64), dim3(256), 0, stream, W, Wt);
  hipLaunchKernelGGL(gemm_qkv, dim3(48, 64), dim3(256), 0, stream, xb, Wt, bias, qkv);
  hipLaunchKernelGGL(norm_rope, dim3(8192, 4), dim3(256), 0, stream, qkv, rot, qw, kw, Qb, Kb, Vb);
  hipLaunchKernelGGL(transpose_v, dim3(64, 2, 32), dim3(256), 0, stream, Vb, Vt);
  hipLaunchKernelGGL(attn, dim3(32, 32), dim3(256), 0, stream, Qb, Kb, Vt, out);
}

// Round 4
// 909.835 us; speedup vs baseline: 2.1484x; 2.1484x over previous
//
#include <hip/hip_runtime.h>

// Problem constants (fixed by reference)
#define DIM 2048
#define NH 16
#define HD 128
#define NB 2
#define SEQ 4096
#define QKVC (3*DIM)            // 6144
#define EPS 1e-6f
#define LOG2E 1.4426950408889634f
#define SM_SCALE 0.08838834764831845f  // 1/sqrt(128)

typedef unsigned short u16;
typedef unsigned int u32;
typedef __attribute__((ext_vector_type(8))) short bf16x8;   // 8 bf16 = 4 VGPR (guide §3)
typedef __attribute__((ext_vector_type(4))) float f32x4;

#define GAS __attribute__((address_space(1)))
#define LAS __attribute__((address_space(3)))

// async global->LDS, 16B per lane, LDS dest = wave-uniform base + lane*16
__device__ __forceinline__ void gl_lds16(const void* g, void* l) {
  __builtin_amdgcn_global_load_lds((const GAS void*)g, (LAS void*)l, 16, 0, 0);
}

__device__ __forceinline__ u16 f2bf(float f) {   // RNE f32 -> bf16
  u32 u = __float_as_uint(f);
  u += 0x7fffu + ((u >> 16) & 1u);
  return (u16)(u >> 16);
}
__device__ __forceinline__ float bf2f(u32 h) { return __uint_as_float(h << 16); }

// pack two f32 -> two bf16 (round-half-up) in one u32: [hi16(e1) | hi16(e0)]
__device__ __forceinline__ u32 pack_bf2(float e0, float e1) {
  u32 a = __float_as_uint(e1) + 0x8000u;
  u32 b = __float_as_uint(e0) + 0x8000u;
  return __builtin_amdgcn_perm(a, b, 0x07060302u);
}

// ---------------- kernel 1: x fp32 -> bf16 ----------------
__global__ __launch_bounds__(256) void cast_x(const float* __restrict__ x,
                                              u16* __restrict__ xb) {
  int i = (blockIdx.x * 256 + threadIdx.x) * 4;
  float4 v = *(const float4*)(x + i);
  u16 o0 = f2bf(v.x), o1 = f2bf(v.y), o2 = f2bf(v.z), o3 = f2bf(v.w);
  *(ushort4*)(xb + i) = make_ushort4(o0, o1, o2, o3);
}

// ---------------- kernel 2: W (2048x6144) fp32 -> Wt (6144x2048) bf16 ----------------
__global__ __launch_bounds__(256) void cast_tw(const float* __restrict__ W,
                                               u16* __restrict__ Wt) {
  __shared__ u16 t[32][33];
  int n0 = blockIdx.x * 32, k0 = blockIdx.y * 32;
  int x = threadIdx.x & 31, y = threadIdx.x >> 5;      // y in 0..7
#pragma unroll
  for (int i = 0; i < 4; i++) {
    int r = y + 8 * i;
    t[r][x] = f2bf(W[(size_t)(k0 + r) * QKVC + n0 + x]);
  }
  __syncthreads();
#pragma unroll
  for (int i = 0; i < 4; i++) {
    int r = y + 8 * i;
    Wt[(size_t)(n0 + r) * DIM + k0 + x] = t[x][r];
  }
}

// ---------------- kernel 3: qkv = xb @ Wt^T + bias (bf16 MFMA, m97 structure) ----------------
__global__ __launch_bounds__(256) void gemm_qkv(const u16* __restrict__ A,   // 8192x2048
                                                const u16* __restrict__ Bt,  // 6144x2048
                                                const float* __restrict__ bias,
                                                u16* __restrict__ C) {       // 8192x6144 bf16
  __shared__ __align__(16) u16 As[128 * 64];
  __shared__ __align__(16) u16 Bs[128 * 64];
  const int nt = blockIdx.x, mt = blockIdx.y;
  const int tid = threadIdx.x, w = tid >> 6, l = tid & 63;
  const int wm = (w & 1) * 64, wn = (w >> 1) * 64;
  const int lr = l & 15, quad = l >> 4;
  const int srow = l >> 3, scol = (l & 7) * 8;   // staging: 8 rows x 128B per 1KB issue
  f32x4 acc[4][4] = {};
  for (int k0 = 0; k0 < DIM; k0 += 64) {
#pragma unroll
    for (int i = 0; i < 4; i++) {
      int r = w * 32 + i * 8 + srow;
      gl_lds16(A + (size_t)(mt * 128 + r) * DIM + k0 + scol, As + (w * 32 + i * 8) * 64);
      gl_lds16(Bt + (size_t)(nt * 128 + r) * DIM + k0 + scol, Bs + (w * 32 + i * 8) * 64);
    }
    __syncthreads();
#pragma unroll
    for (int kk = 0; kk < 2; kk++) {
      bf16x8 a[4], b[4];
#pragma unroll
      for (int mi = 0; mi < 4; mi++)
        a[mi] = *(const bf16x8*)(As + (wm + mi * 16 + lr) * 64 + kk * 32 + quad * 8);
#pragma unroll
      for (int ni = 0; ni < 4; ni++)
        b[ni] = *(const bf16x8*)(Bs + (wn + ni * 16 + lr) * 64 + kk * 32 + quad * 8);
#pragma unroll
      for (int mi = 0; mi < 4; mi++)
#pragma unroll
        for (int ni = 0; ni < 4; ni++)
          acc[mi][ni] = __builtin_amdgcn_mfma_f32_16x16x32_bf16(a[mi], b[ni], acc[mi][ni], 0, 0, 0);
    }
    __syncthreads();
  }
  // epilogue: + bias, bf16 store. C/D layout: col=lane&15, row=quad*4+reg (m89/m91)
#pragma unroll
  for (int ni = 0; ni < 4; ni++) {
    int col = nt * 128 + wn + ni * 16 + lr;
    float bv = bias[col];
#pragma unroll
    for (int mi = 0; mi < 4; mi++) {
      int row = mt * 128 + wm + mi * 16 + quad * 4;
#pragma unroll
      for (int r = 0; r < 4; r++)
        C[(size_t)(row + r) * QKVC + col] = f2bf(acc[mi][ni][r] + bv);
    }
  }
}

// ---------------- kernel 4: RMSNorm + RoPE, split into Q,K,V (b,h,n,d) bf16 ----------------
// one wave per (token, head); lane l owns dims (2l, 2l+1) = one RoPE pair
// Q is pre-scaled by SM_SCALE*LOG2E so attn's exp2 needs no per-score multiply.
__global__ __launch_bounds__(256) void norm_rope(const u16* __restrict__ qkv,
                                                 const float* __restrict__ rot,
                                                 const float* __restrict__ qw,
                                                 const float* __restrict__ kw,
                                                 u16* __restrict__ Q, u16* __restrict__ K,
                                                 u16* __restrict__ V) {
  const int tok = blockIdx.x;                       // 0..8191  (b*4096+n)
  const int h = blockIdx.y * 4 + (threadIdx.x >> 6);
  const int l = threadIdx.x & 63;
  const int n = tok & (SEQ - 1);
  const size_t base = (size_t)tok * QKVC + h * 384 + 6 * l;  // elems; layout (d,j), j innermost
  const u32* p = (const u32*)(qkv + base);
  u32 u0 = p[0], u1 = p[1], u2 = p[2];
  float q0 = bf2f(u0 & 0xffff), k0 = bf2f(u0 >> 16);
  float v0 = bf2f(u1 & 0xffff), q1 = bf2f(u1 >> 16);
  float k1 = bf2f(u2 & 0xffff), v1 = bf2f(u2 >> 16);
  float sq = q0 * q0 + q1 * q1, sk = k0 * k0 + k1 * k1;
#pragma unroll
  for (int m = 1; m < 64; m <<= 1) {
    sq += __shfl_xor(sq, m, 64);
    sk += __shfl_xor(sk, m, 64);
  }
  float rq = rsqrtf(sq * (1.0f / HD) + EPS) * (SM_SCALE * LOG2E);  // scale folded into Q
  float rk = rsqrtf(sk * (1.0f / HD) + EPS);
  float2 wq = *(const float2*)(qw + 2 * l);
  float2 wk = *(const float2*)(kw + 2 * l);
  float4 rr = *(const float4*)(rot + (size_t)(n * 64 + l) * 4);  // [cos,-sin,sin,cos]
  float qh0 = q0 * rq * wq.x, qh1 = q1 * rq * wq.y;
  float kh0 = k0 * rk * wk.x, kh1 = k1 * rk * wk.y;
  float qo0 = rr.x * qh0 + rr.y * qh1, qo1 = rr.z * qh0 + rr.w * qh1;
  float ko0 = rr.x * kh0 + rr.y * kh1, ko1 = rr.z * kh0 + rr.w * kh1;
  const int bh = (tok >> 12) * NH + h;
  size_t o = ((size_t)bh * SEQ + n) * HD + 2 * l;
  *(u32*)(Q + o) = (u32)f2bf(qo0) | ((u32)f2bf(qo1) << 16);
  *(u32*)(K + o) = (u32)f2bf(ko0) | ((u32)f2bf(ko1) << 16);
  *(u32*)(V + o) = (u32)f2bf(v0) | ((u32)f2bf(v1) << 16);
}

// ---------------- kernel 5: V (bh,n,d) -> Vt (bh,d,n) ----------------
__global__ __launch_bounds__(256) void transpose_v(const u16* __restrict__ V,
                                                   u16* __restrict__ Vt) {
  __shared__ u16 t[64][65];
  const int nt = blockIdx.x, dt = blockIdx.y, bh = blockIdx.z;
  const int x = threadIdx.x & 63, y = threadIdx.x >> 6;   // y 0..3
  const size_t vb = (size_t)bh * SEQ * HD;
#pragma unroll
  for (int i = 0; i < 16; i++) {
    int r = y + 4 * i;
    t[r][x] = V[vb + (size_t)(nt * 64 + r) * HD + dt * 64 + x];
  }
  __syncthreads();
  const size_t ob = (size_t)bh * HD * SEQ;
#pragma unroll
  for (int i = 0; i < 16; i++) {
    int r = y + 4 * i;
    Vt[ob + (size_t)(dt * 64 + r) * SEQ + nt * 64 + x] = t[x][r];
  }
}

// ---------------- kernel 6: flash attention (S^T form, maxless softmax, mi=4) ----------------
// block = (qt, bh): 256 Q rows; wave w owns Q rows w*64..w*64+63 (4 x 16-row MFMA tiles).
// Widened to 64 Q rows/wave so each kf/vf b128 LDS read feeds 4 MFMAs (was 2):
// halves LDS-pipe time per FLOP -> MFMA becomes the binding pipe.
// S^T = mfma(kf, qf): lanes = qrows, (quad,reg) = keys. Key permutation in Ks staging
// makes exp(S^T) pack in-register into a K=32 B-operand for O^T = mfma(vf, pf).
// Maxless softmax: |score*scale*log2e| <= 16.3 -> fp32 exp2 safe.
// Q arrives pre-scaled by SM_SCALE*LOG2E (folded in norm_rope).
// XOR chunk swizzle (chunk ^= row&7) on Ks/Vs kills the 16-way bank conflicts.
// Registers: oacc 128 (AGPR) + qf 64 + temps ~60 -> NO min-waves bound (R3: forcing
// occupancy spilled accumulators to scratch, 6.9 GB of HBM traffic, 4x slower).
__global__ __launch_bounds__(256) void attn(const u16* __restrict__ Q,
                                            const u16* __restrict__ K,
                                            const u16* __restrict__ Vt,
                                            float* __restrict__ out) {
  __shared__ __align__(16) u16 smem[8192 + 8192];  // Ks 64x128 + Vs 128x64 = 32 KB
  u16* Ks = smem;
  u16* Vs = smem + 8192;
  const int qt = blockIdx.x, bh = blockIdx.y;
  const int tid = threadIdx.x, w = tid >> 6, l = tid & 63;
  const int lr = l & 15, quad = l >> 4;
  const size_t qb = (size_t)bh * SEQ * HD;
  const size_t vb = (size_t)bh * HD * SEQ;

  // Q fragments direct from global (B-operand: n=qrow on lanes, k=quad*8+j)
  bf16x8 qf[4][4];
#pragma unroll
  for (int mi = 0; mi < 4; mi++)
#pragma unroll
    for (int ks = 0; ks < 4; ks++)
      qf[mi][ks] = *(const bf16x8*)(Q + qb + (size_t)(qt * 256 + w * 64 + mi * 16 + lr) * HD +
                                    ks * 32 + quad * 8);

  f32x4 oacc[4][8] = {};
  float lacc[4] = {0.f, 0.f, 0.f, 0.f};

  for (int kt = 0; kt < SEQ / 64; kt++) {
    // ---- stage K tile: 64 rows x 128 u16. LDS row rl holds PERMUTED key:
    //   rem=rl&31: key = (rl&32) + ((rem>>2)&3)*8 + (rem>>4)*4 + (rem&3)
    // column chunks xor-swizzled by (rl&7).
#pragma unroll
    for (int i = 0; i < 4; i++) {
      int rl = w * 16 + i * 4 + (l >> 4);
      int rem = rl & 31;
      int key = (rl & 32) + ((rem >> 2) & 3) * 8 + ((rem >> 4) << 2) + (rem & 3);
      int lc = (l & 15) ^ (rl & 7);
      gl_lds16(K + qb + (size_t)(kt * 64 + key) * HD + lc * 8, Ks + (w * 16 + i * 4) * 128);
    }
    // ---- stage V tile: 128 d-rows x 64 keys (natural key order), chunk-swizzled
#pragma unroll
    for (int i = 0; i < 4; i++) {
      int row = w * 32 + i * 8 + (l >> 3);
      int lc = (l & 7) ^ (row & 7);
      gl_lds16(Vt + vb + (size_t)row * SEQ + kt * 64 + lc * 8, Vs + (w * 32 + i * 8) * 64);
    }
    __syncthreads();

#pragma unroll
    for (int g = 0; g < 2; g++) {          // two 32-key groups per tile
      // S^T tiles: s[mi][u], lane holds (key = 32g+8*quad+4u+r, qrow = mi-tile + lr)
      f32x4 s[4][2] = {};
#pragma unroll
      for (int u = 0; u < 2; u++) {
        // K fragments (A-operand: m=key-slot on lanes, k=d); each read feeds 4 MFMAs
        bf16x8 kf[4];
#pragma unroll
        for (int ks = 0; ks < 4; ks++) {
          int row = g * 32 + u * 16 + lr;
          int ch = (ks * 4 + quad) ^ (row & 7);
          kf[ks] = *(const bf16x8*)(Ks + row * 128 + ch * 8);
        }
#pragma unroll
        for (int ks = 0; ks < 4; ks++)
#pragma unroll
          for (int mi = 0; mi < 4; mi++)
            s[mi][u] = __builtin_amdgcn_mfma_f32_16x16x32_bf16(kf[ks], qf[mi][ks], s[mi][u], 0, 0, 0);
      }
      // exp (scale pre-folded into Q), accumulate l (fp32), pack P (round-half-up,
      // one v_perm per pair) as K=32 B-operand: j=4u+r -> key = 32g+8*quad+j
      bf16x8 pf[4];
#pragma unroll
      for (int mi = 0; mi < 4; mi++) {
#pragma unroll
        for (int u = 0; u < 2; u++)
#pragma unroll
          for (int r = 0; r < 4; r++) {
            float p = exp2f(s[mi][u][r]);
            s[mi][u][r] = p;
            lacc[mi] += p;
          }
        union { u32 w4[4]; bf16x8 v; } pk;
#pragma unroll
        for (int u = 0; u < 2; u++) {
          pk.w4[u * 2 + 0] = pack_bf2(s[mi][u][0], s[mi][u][1]);
          pk.w4[u * 2 + 1] = pack_bf2(s[mi][u][2], s[mi][u][3]);
        }
        pf[mi] = pk.v;
      }
      // O^T += V^T P^T : A = Vs[d][key] frag, B = pf. Result: m=d, lanes=qrow.
      // Each vf read feeds 4 MFMAs.
#pragma unroll
      for (int di = 0; di < 8; di++) {
        int row = di * 16 + lr;
        int ch = (4 * g + quad) ^ (row & 7);
        bf16x8 vf = *(const bf16x8*)(Vs + row * 64 + ch * 8);
#pragma unroll
        for (int mi = 0; mi < 4; mi++)
          oacc[mi][di] = __builtin_amdgcn_mfma_f32_16x16x32_bf16(vf, pf[mi], oacc[mi][di], 0, 0, 0);
      }
    }
    __syncthreads();   // Ks/Vs safe to overwrite next iter
  }

  // epilogue: reduce l across quads (2 shuffles, once), divide, coalesced float4 stores
  const int b = bh >> 4, h = bh & 15;
#pragma unroll
  for (int mi = 0; mi < 4; mi++) {
    float lsum = lacc[mi];
    lsum += __shfl_xor(lsum, 16, 64);
    lsum += __shfl_xor(lsum, 32, 64);
    float inv = 1.0f / lsum;
    int row = qt * 256 + w * 64 + mi * 16 + lr;
#pragma unroll
    for (int di = 0; di < 8; di++) {
      f32x4 o = oacc[mi][di];
      float4 v4 = make_float4(o[0] * inv, o[1] * inv, o[2] * inv, o[3] * inv);
      *(float4*)(out + ((size_t)(b * SEQ + row)) * DIM + h * HD + di * 16 + quad * 4) = v4;
    }
  }
}

// ---------------- launch ----------------
// ws layout (u16 elems; aliases are ordered by stream serialization):
//  [0        , 16777216)  xb   (later reused as Qb)
//  [16777216 , 29360128)  Wt
//  [29360128 , 79691776)  qkv  (first 16.8M elems later reused as Vt)
//  [79691776 , 96468992)  Kb
//  [96468992 ,113246208)  Vb
// total 226,492,416 bytes required of ws_size.
extern "C" void kernel_launch(void* const* d_in, const int* in_sizes, int n_in,
                              void* d_out, int out_size, void* d_ws, size_t ws_size,
                              hipStream_t stream) {
  (void)in_sizes; (void)n_in; (void)out_size; (void)ws_size;
  const float* x    = (const float*)d_in[0];
  const float* rot  = (const float*)d_in[1];
  const float* W    = (const float*)d_in[2];
  const float* bias = (const float*)d_in[3];
  const float* qw   = (const float*)d_in[4];
  const float* kw   = (const float*)d_in[5];
  float* out = (float*)d_out;
  u16* ws  = (u16*)d_ws;
  u16* xb  = ws;
  u16* Wt  = ws + 16777216;
  u16* qkv = ws + 29360128;
  u16* Qb  = ws;               // alias xb (dead after gemm)
  u16* Vt  = ws + 29360128;    // alias qkv (dead after norm_rope)
  u16* Kb  = ws + 79691776;
  u16* Vb  = ws + 96468992;

  hipLaunchKernelGGL(cast_x, dim3(16384), dim3(256), 0, stream, x, xb);
  hipLaunchKernelGGL(cast_tw, dim3(192, 64), dim3(256), 0, stream, W, Wt);
  hipLaunchKernelGGL(gemm_qkv, dim3(48, 64), dim3(256), 0, stream, xb, Wt, bias, qkv);
  hipLaunchKernelGGL(norm_rope, dim3(8192, 4), dim3(256), 0, stream, qkv, rot, qw, kw, Qb, Kb, Vb);
  hipLaunchKernelGGL(transpose_v, dim3(64, 2, 32), dim3(256), 0, stream, Vb, Vt);
  hipLaunchKernelGGL(attn, dim3(16, 32), dim3(256), 0, stream, Qb, Kb, Vt, out);
}

// Round 5
// 795.027 us; speedup vs baseline: 2.4586x; 1.1444x over previous
//
#include <hip/hip_runtime.h>

// Problem constants (fixed by reference)
#define DIM 2048
#define NH 16
#define HD 128
#define NB 2
#define SEQ 4096
#define QKVC (3*DIM)            // 6144
#define EPS 1e-6f
#define LOG2E 1.4426950408889634f
#define SM_SCALE 0.08838834764831845f  // 1/sqrt(128)

typedef unsigned short u16;
typedef unsigned int u32;
typedef __attribute__((ext_vector_type(8))) short bf16x8;   // 8 bf16 = 4 VGPR (guide §3)
typedef __attribute__((ext_vector_type(4))) float f32x4;

#define GAS __attribute__((address_space(1)))
#define LAS __attribute__((address_space(3)))

// async global->LDS, 16B per lane, LDS dest = wave-uniform base + lane*16
__device__ __forceinline__ void gl_lds16(const void* g, void* l) {
  __builtin_amdgcn_global_load_lds((const GAS void*)g, (LAS void*)l, 16, 0, 0);
}

__device__ __forceinline__ u16 f2bf(float f) {   // RNE f32 -> bf16
  u32 u = __float_as_uint(f);
  u += 0x7fffu + ((u >> 16) & 1u);
  return (u16)(u >> 16);
}
__device__ __forceinline__ float bf2f(u32 h) { return __uint_as_float(h << 16); }

// pack two f32 -> two bf16 (round-half-up) in one u32: [hi16(e1) | hi16(e0)]
__device__ __forceinline__ u32 pack_bf2(float e0, float e1) {
  u32 a = __float_as_uint(e1) + 0x8000u;
  u32 b = __float_as_uint(e0) + 0x8000u;
  return __builtin_amdgcn_perm(a, b, 0x07060302u);
}

// ---------------- kernel 1: x fp32 -> bf16 ----------------
__global__ __launch_bounds__(256) void cast_x(const float* __restrict__ x,
                                              u16* __restrict__ xb) {
  int i = (blockIdx.x * 256 + threadIdx.x) * 4;
  float4 v = *(const float4*)(x + i);
  u16 o0 = f2bf(v.x), o1 = f2bf(v.y), o2 = f2bf(v.z), o3 = f2bf(v.w);
  *(ushort4*)(xb + i) = make_ushort4(o0, o1, o2, o3);
}

// ---------------- kernel 2: W (2048x6144) fp32 -> Wt (6144x2048) bf16 ----------------
__global__ __launch_bounds__(256) void cast_tw(const float* __restrict__ W,
                                               u16* __restrict__ Wt) {
  __shared__ u16 t[32][33];
  int n0 = blockIdx.x * 32, k0 = blockIdx.y * 32;
  int x = threadIdx.x & 31, y = threadIdx.x >> 5;      // y in 0..7
#pragma unroll
  for (int i = 0; i < 4; i++) {
    int r = y + 8 * i;
    t[r][x] = f2bf(W[(size_t)(k0 + r) * QKVC + n0 + x]);
  }
  __syncthreads();
#pragma unroll
  for (int i = 0; i < 4; i++) {
    int r = y + 8 * i;
    Wt[(size_t)(n0 + r) * DIM + k0 + x] = t[x][r];
  }
}

// ---------------- kernel 3: qkv = xb @ Wt^T + bias (bf16 MFMA, m97 structure) ----------------
__global__ __launch_bounds__(256) void gemm_qkv(const u16* __restrict__ A,   // 8192x2048
                                                const u16* __restrict__ Bt,  // 6144x2048
                                                const float* __restrict__ bias,
                                                u16* __restrict__ C) {       // 8192x6144 bf16
  __shared__ __align__(16) u16 As[128 * 64];
  __shared__ __align__(16) u16 Bs[128 * 64];
  const int nt = blockIdx.x, mt = blockIdx.y;
  const int tid = threadIdx.x, w = tid >> 6, l = tid & 63;
  const int wm = (w & 1) * 64, wn = (w >> 1) * 64;
  const int lr = l & 15, quad = l >> 4;
  const int srow = l >> 3, scol = (l & 7) * 8;   // staging: 8 rows x 128B per 1KB issue
  f32x4 acc[4][4] = {};
  for (int k0 = 0; k0 < DIM; k0 += 64) {
#pragma unroll
    for (int i = 0; i < 4; i++) {
      int r = w * 32 + i * 8 + srow;
      gl_lds16(A + (size_t)(mt * 128 + r) * DIM + k0 + scol, As + (w * 32 + i * 8) * 64);
      gl_lds16(Bt + (size_t)(nt * 128 + r) * DIM + k0 + scol, Bs + (w * 32 + i * 8) * 64);
    }
    __syncthreads();
#pragma unroll
    for (int kk = 0; kk < 2; kk++) {
      bf16x8 a[4], b[4];
#pragma unroll
      for (int mi = 0; mi < 4; mi++)
        a[mi] = *(const bf16x8*)(As + (wm + mi * 16 + lr) * 64 + kk * 32 + quad * 8);
#pragma unroll
      for (int ni = 0; ni < 4; ni++)
        b[ni] = *(const bf16x8*)(Bs + (wn + ni * 16 + lr) * 64 + kk * 32 + quad * 8);
#pragma unroll
      for (int mi = 0; mi < 4; mi++)
#pragma unroll
        for (int ni = 0; ni < 4; ni++)
          acc[mi][ni] = __builtin_amdgcn_mfma_f32_16x16x32_bf16(a[mi], b[ni], acc[mi][ni], 0, 0, 0);
    }
    __syncthreads();
  }
  // epilogue: + bias, bf16 store. C/D layout: col=lane&15, row=quad*4+reg (m89/m91)
#pragma unroll
  for (int ni = 0; ni < 4; ni++) {
    int col = nt * 128 + wn + ni * 16 + lr;
    float bv = bias[col];
#pragma unroll
    for (int mi = 0; mi < 4; mi++) {
      int row = mt * 128 + wm + mi * 16 + quad * 4;
#pragma unroll
      for (int r = 0; r < 4; r++)
        C[(size_t)(row + r) * QKVC + col] = f2bf(acc[mi][ni][r] + bv);
    }
  }
}

// ---------------- kernel 4: RMSNorm + RoPE, split into Q,K,V (b,h,n,d) bf16 ----------------
// one wave per (token, head); lane l owns dims (2l, 2l+1) = one RoPE pair
// Q is pre-scaled by SM_SCALE*LOG2E so attn's exp2 needs no per-score multiply.
__global__ __launch_bounds__(256) void norm_rope(const u16* __restrict__ qkv,
                                                 const float* __restrict__ rot,
                                                 const float* __restrict__ qw,
                                                 const float* __restrict__ kw,
                                                 u16* __restrict__ Q, u16* __restrict__ K,
                                                 u16* __restrict__ V) {
  const int tok = blockIdx.x;                       // 0..8191  (b*4096+n)
  const int h = blockIdx.y * 4 + (threadIdx.x >> 6);
  const int l = threadIdx.x & 63;
  const int n = tok & (SEQ - 1);
  const size_t base = (size_t)tok * QKVC + h * 384 + 6 * l;  // elems; layout (d,j), j innermost
  const u32* p = (const u32*)(qkv + base);
  u32 u0 = p[0], u1 = p[1], u2 = p[2];
  float q0 = bf2f(u0 & 0xffff), k0 = bf2f(u0 >> 16);
  float v0 = bf2f(u1 & 0xffff), q1 = bf2f(u1 >> 16);
  float k1 = bf2f(u2 & 0xffff), v1 = bf2f(u2 >> 16);
  float sq = q0 * q0 + q1 * q1, sk = k0 * k0 + k1 * k1;
#pragma unroll
  for (int m = 1; m < 64; m <<= 1) {
    sq += __shfl_xor(sq, m, 64);
    sk += __shfl_xor(sk, m, 64);
  }
  float rq = rsqrtf(sq * (1.0f / HD) + EPS) * (SM_SCALE * LOG2E);  // scale folded into Q
  float rk = rsqrtf(sk * (1.0f / HD) + EPS);
  float2 wq = *(const float2*)(qw + 2 * l);
  float2 wk = *(const float2*)(kw + 2 * l);
  float4 rr = *(const float4*)(rot + (size_t)(n * 64 + l) * 4);  // [cos,-sin,sin,cos]
  float qh0 = q0 * rq * wq.x, qh1 = q1 * rq * wq.y;
  float kh0 = k0 * rk * wk.x, kh1 = k1 * rk * wk.y;
  float qo0 = rr.x * qh0 + rr.y * qh1, qo1 = rr.z * qh0 + rr.w * qh1;
  float ko0 = rr.x * kh0 + rr.y * kh1, ko1 = rr.z * kh0 + rr.w * kh1;
  const int bh = (tok >> 12) * NH + h;
  size_t o = ((size_t)bh * SEQ + n) * HD + 2 * l;
  *(u32*)(Q + o) = (u32)f2bf(qo0) | ((u32)f2bf(qo1) << 16);
  *(u32*)(K + o) = (u32)f2bf(ko0) | ((u32)f2bf(ko1) << 16);
  *(u32*)(V + o) = (u32)f2bf(v0) | ((u32)f2bf(v1) << 16);
}

// ---------------- kernel 5: V (bh,n,d) -> Vt (bh,d,n) ----------------
__global__ __launch_bounds__(256) void transpose_v(const u16* __restrict__ V,
                                                   u16* __restrict__ Vt) {
  __shared__ u16 t[64][65];
  const int nt = blockIdx.x, dt = blockIdx.y, bh = blockIdx.z;
  const int x = threadIdx.x & 63, y = threadIdx.x >> 6;   // y 0..3
  const size_t vb = (size_t)bh * SEQ * HD;
#pragma unroll
  for (int i = 0; i < 16; i++) {
    int r = y + 4 * i;
    t[r][x] = V[vb + (size_t)(nt * 64 + r) * HD + dt * 64 + x];
  }
  __syncthreads();
  const size_t ob = (size_t)bh * HD * SEQ;
#pragma unroll
  for (int i = 0; i < 16; i++) {
    int r = y + 4 * i;
    Vt[ob + (size_t)(dt * 64 + r) * SEQ + nt * 64 + x] = t[x][r];
  }
}

// ---------------- kernel 6: flash attention (S^T form, maxless softmax, mi=2) ----------------
// block = (qt, bh): 128 Q rows; wave w owns Q rows w*32..w*32+31 (2 x 16-row MFMA tiles).
// REGISTER KNIFE-EDGE (R3/R4 lessons): the unified VGPR+AGPR budget must stay <=256/wave
// for 2 waves/SIMD. mi=2 needs ~190 (oacc 64 AGPR + qf 32 + temps) -> fits; mi=4 needed
// ~290 -> 1 wave/SIMD, pipes serialized, 25% slower. (256,2) is a SAFE cap (no spill);
// (256,4)=128 regs spilled accumulators to scratch (6.9 GB HBM traffic, 4x slower).
// S^T = mfma(kf, qf): lanes = qrows, (quad,reg) = keys. Key permutation in Ks staging
// makes exp(S^T) pack in-register into a K=32 B-operand for O^T = mfma(vf, pf).
// Maxless softmax: |score*scale*log2e| <= 16.3 -> fp32 exp2 safe.
// Q arrives pre-scaled by SM_SCALE*LOG2E (folded in norm_rope).
// XOR chunk swizzle (chunk ^= row&7) on Ks/Vs kills the 16-way bank conflicts.
__global__ __launch_bounds__(256, 2) void attn(const u16* __restrict__ Q,
                                               const u16* __restrict__ K,
                                               const u16* __restrict__ Vt,
                                               float* __restrict__ out) {
  __shared__ __align__(16) u16 smem[8192 + 8192];  // Ks 64x128 + Vs 128x64 = 32 KB
  u16* Ks = smem;
  u16* Vs = smem + 8192;
  const int qt = blockIdx.x, bh = blockIdx.y;
  const int tid = threadIdx.x, w = tid >> 6, l = tid & 63;
  const int lr = l & 15, quad = l >> 4;
  const size_t qb = (size_t)bh * SEQ * HD;
  const size_t vb = (size_t)bh * HD * SEQ;

  // Q fragments direct from global (B-operand: n=qrow on lanes, k=quad*8+j)
  bf16x8 qf[2][4];
#pragma unroll
  for (int mi = 0; mi < 2; mi++)
#pragma unroll
    for (int ks = 0; ks < 4; ks++)
      qf[mi][ks] = *(const bf16x8*)(Q + qb + (size_t)(qt * 128 + w * 32 + mi * 16 + lr) * HD +
                                    ks * 32 + quad * 8);

  f32x4 oacc[2][8] = {};
  float lacc[2] = {0.f, 0.f};

  for (int kt = 0; kt < SEQ / 64; kt++) {
    // ---- stage K tile: 64 rows x 128 u16. LDS row rl holds PERMUTED key:
    //   rem=rl&31: key = (rl&32) + ((rem>>2)&3)*8 + (rem>>4)*4 + (rem&3)
    // column chunks xor-swizzled by (rl&7).
#pragma unroll
    for (int i = 0; i < 4; i++) {
      int rl = w * 16 + i * 4 + (l >> 4);
      int rem = rl & 31;
      int key = (rl & 32) + ((rem >> 2) & 3) * 8 + ((rem >> 4) << 2) + (rem & 3);
      int lc = (l & 15) ^ (rl & 7);
      gl_lds16(K + qb + (size_t)(kt * 64 + key) * HD + lc * 8, Ks + (w * 16 + i * 4) * 128);
    }
    // ---- stage V tile: 128 d-rows x 64 keys (natural key order), chunk-swizzled
#pragma unroll
    for (int i = 0; i < 4; i++) {
      int row = w * 32 + i * 8 + (l >> 3);
      int lc = (l & 7) ^ (row & 7);
      gl_lds16(Vt + vb + (size_t)row * SEQ + kt * 64 + lc * 8, Vs + (w * 32 + i * 8) * 64);
    }
    __syncthreads();

#pragma unroll
    for (int g = 0; g < 2; g++) {          // two 32-key groups per tile
      // S^T tiles: s[mi][u], lane holds (key = 32g+8*quad+4u+r, qrow = mi-tile + lr)
      f32x4 s[2][2] = {};
#pragma unroll
      for (int u = 0; u < 2; u++) {
        // K fragments (A-operand: m=key-slot on lanes, k=d); each read feeds 2 MFMAs
        bf16x8 kf[4];
#pragma unroll
        for (int ks = 0; ks < 4; ks++) {
          int row = g * 32 + u * 16 + lr;
          int ch = (ks * 4 + quad) ^ (row & 7);
          kf[ks] = *(const bf16x8*)(Ks + row * 128 + ch * 8);
        }
#pragma unroll
        for (int ks = 0; ks < 4; ks++)
#pragma unroll
          for (int mi = 0; mi < 2; mi++)
            s[mi][u] = __builtin_amdgcn_mfma_f32_16x16x32_bf16(kf[ks], qf[mi][ks], s[mi][u], 0, 0, 0);
      }
      // exp (scale pre-folded into Q), accumulate l (fp32), pack P (round-half-up,
      // one v_perm per pair) as K=32 B-operand: j=4u+r -> key = 32g+8*quad+j
      bf16x8 pf[2];
#pragma unroll
      for (int mi = 0; mi < 2; mi++) {
#pragma unroll
        for (int u = 0; u < 2; u++)
#pragma unroll
          for (int r = 0; r < 4; r++) {
            float p = exp2f(s[mi][u][r]);
            s[mi][u][r] = p;
            lacc[mi] += p;
          }
        union { u32 w4[4]; bf16x8 v; } pk;
#pragma unroll
        for (int u = 0; u < 2; u++) {
          pk.w4[u * 2 + 0] = pack_bf2(s[mi][u][0], s[mi][u][1]);
          pk.w4[u * 2 + 1] = pack_bf2(s[mi][u][2], s[mi][u][3]);
        }
        pf[mi] = pk.v;
      }
      // O^T += V^T P^T : A = Vs[d][key] frag, B = pf. Result: m=d, lanes=qrow.
#pragma unroll
      for (int di = 0; di < 8; di++) {
        int row = di * 16 + lr;
        int ch = (4 * g + quad) ^ (row & 7);
        bf16x8 vf = *(const bf16x8*)(Vs + row * 64 + ch * 8);
#pragma unroll
        for (int mi = 0; mi < 2; mi++)
          oacc[mi][di] = __builtin_amdgcn_mfma_f32_16x16x32_bf16(vf, pf[mi], oacc[mi][di], 0, 0, 0);
      }
    }
    __syncthreads();   // Ks/Vs safe to overwrite next iter
  }

  // epilogue: reduce l across quads (2 shuffles, once), divide, coalesced float4 stores
  const int b = bh >> 4, h = bh & 15;
#pragma unroll
  for (int mi = 0; mi < 2; mi++) {
    float lsum = lacc[mi];
    lsum += __shfl_xor(lsum, 16, 64);
    lsum += __shfl_xor(lsum, 32, 64);
    float inv = 1.0f / lsum;
    int row = qt * 128 + w * 32 + mi * 16 + lr;
#pragma unroll
    for (int di = 0; di < 8; di++) {
      f32x4 o = oacc[mi][di];
      float4 v4 = make_float4(o[0] * inv, o[1] * inv, o[2] * inv, o[3] * inv);
      *(float4*)(out + ((size_t)(b * SEQ + row)) * DIM + h * HD + di * 16 + quad * 4) = v4;
    }
  }
}

// ---------------- launch ----------------
// ws layout (u16 elems; aliases are ordered by stream serialization):
//  [0        , 16777216)  xb   (later reused as Qb)
//  [16777216 , 29360128)  Wt
//  [29360128 , 79691776)  qkv  (first 16.8M elems later reused as Vt)
//  [79691776 , 96468992)  Kb
//  [96468992 ,113246208)  Vb
// total 226,492,416 bytes required of ws_size.
extern "C" void kernel_launch(void* const* d_in, const int* in_sizes, int n_in,
                              void* d_out, int out_size, void* d_ws, size_t ws_size,
                              hipStream_t stream) {
  (void)in_sizes; (void)n_in; (void)out_size; (void)ws_size;
  const float* x    = (const float*)d_in[0];
  const float* rot  = (const float*)d_in[1];
  const float* W    = (const float*)d_in[2];
  const float* bias = (const float*)d_in[3];
  const float* qw   = (const float*)d_in[4];
  const float* kw   = (const float*)d_in[5];
  float* out = (float*)d_out;
  u16* ws  = (u16*)d_ws;
  u16* xb  = ws;
  u16* Wt  = ws + 16777216;
  u16* qkv = ws + 29360128;
  u16* Qb  = ws;               // alias xb (dead after gemm)
  u16* Vt  = ws + 29360128;    // alias qkv (dead after norm_rope)
  u16* Kb  = ws + 79691776;
  u16* Vb  = ws + 96468992;

  hipLaunchKernelGGL(cast_x, dim3(16384), dim3(256), 0, stream, x, xb);
  hipLaunchKernelGGL(cast_tw, dim3(192, 64), dim3(256), 0, stream, W, Wt);
  hipLaunchKernelGGL(gemm_qkv, dim3(48, 64), dim3(256), 0, stream, xb, Wt, bias, qkv);
  hipLaunchKernelGGL(norm_rope, dim3(8192, 4), dim3(256), 0, stream, qkv, rot, qw, kw, Qb, Kb, Vb);
  hipLaunchKernelGGL(transpose_v, dim3(64, 2, 32), dim3(256), 0, stream, Vb, Vt);
  hipLaunchKernelGGL(attn, dim3(32, 32), dim3(256), 0, stream, Qb, Kb, Vt, out);
}